// Round 7
// baseline (839.725 us; speedup 1.0000x reference)
//
#include <hip/hip_runtime.h>

#define NDIM 128

// ---------------- edge-index normalization ----------------
// int64 edge_index => odd 32-bit words are 0; int32 => odd words are random
// node ids. ONE block samples 4096 edges; no global atomics (R2: full-E
// single-address atomic detection cost 108 us).
__global__ __launch_bounds__(256) void detect_kernel(
    const int* __restrict__ raw, int* __restrict__ flag, int E) {
    __shared__ int any_nz;
    if (threadIdx.x == 0) any_nz = 0;
    __syncthreads();
    int local = 0;
    const int samples = (E < 4096) ? E : 4096;
#pragma unroll
    for (int j = 0; j < 16; ++j) {
        int i = threadIdx.x * 16 + j;
        if (i < samples) local |= raw[2 * i + 1];
    }
    if (local) atomicOr(&any_nz, 1);   // LDS atomic, cheap
    __syncthreads();
    if (threadIdx.x == 0) *flag = any_nz;   // nonzero -> int32 layout
}

__global__ void convert_kernel(const int* __restrict__ raw, const int* __restrict__ flag,
                               int* __restrict__ idx, int total) {
    int i = blockIdx.x * 256 + threadIdx.x;
    if (i >= total) return;
    idx[i] = (*flag == 0) ? raw[2 * i] : raw[i];
}

// ---------------- CSR build (counting sort by dst) ----------------
__global__ void hist_kernel(const int* __restrict__ idx, int* __restrict__ deg, int E) {
    int i = blockIdx.x * 256 + threadIdx.x;
    if (i < E) atomicAdd(&deg[idx[E + i]], 1);  // dst row
}

// --- device-wide exclusive scan of deg, 3 kernels, tile = 1024 elements ---
__global__ __launch_bounds__(256) void deg_reduce_kernel(
    const int* __restrict__ deg, int* __restrict__ partials, int n) {
    const int base = blockIdx.x * 1024;
    const int tid = threadIdx.x;
    int s = 0;
#pragma unroll
    for (int j = 0; j < 4; ++j) {
        int i = base + tid * 4 + j;
        if (i < n) s += deg[i];
    }
#pragma unroll
    for (int off = 32; off; off >>= 1) s += __shfl_down(s, off);
    __shared__ int ws[4];
    if ((tid & 63) == 0) ws[tid >> 6] = s;
    __syncthreads();
    if (tid == 0) partials[blockIdx.x] = ws[0] + ws[1] + ws[2] + ws[3];
}

__global__ void scan_partials_kernel(int* __restrict__ partials, int nb,
                                     int* __restrict__ row_start, int n) {
    __shared__ int sh[1024];
    const int tid = threadIdx.x;  // 1024 threads
    int v = (tid < nb) ? partials[tid] : 0;
    sh[tid] = v;
    __syncthreads();
    for (int off = 1; off < 1024; off <<= 1) {
        int a = sh[tid];
        int b = (tid >= off) ? sh[tid - off] : 0;
        __syncthreads();
        sh[tid] = a + b;
        __syncthreads();
    }
    if (tid < nb) partials[tid] = (tid == 0) ? 0 : sh[tid - 1];  // exclusive block offset
    if (tid == 0) row_start[n] = sh[1023];                       // total edge count
}

__global__ __launch_bounds__(256) void deg_downsweep_kernel(
    const int* __restrict__ deg, const int* __restrict__ partials,
    int* __restrict__ row_start, int* __restrict__ cursor,
    float* __restrict__ inv_deg, int n) {
    const int base = blockIdx.x * 1024;
    const int tid = threadIdx.x;
    const int i0 = base + tid * 4;
    int d[4];
    int s = 0;
#pragma unroll
    for (int j = 0; j < 4; ++j) {
        int i = i0 + j;
        d[j] = (i < n) ? deg[i] : 0;
        s += d[j];
    }
    const int lane = tid & 63;
    int incl = s;
#pragma unroll
    for (int off = 1; off < 64; off <<= 1) {
        int t = __shfl_up(incl, off);
        if (lane >= off) incl += t;
    }
    __shared__ int wsum[4];
    if (lane == 63) wsum[tid >> 6] = incl;
    __syncthreads();
    int woff = 0;
    const int w = tid >> 6;
    for (int k = 0; k < w; ++k) woff += wsum[k];
    int excl = incl - s + woff + partials[blockIdx.x];
#pragma unroll
    for (int j = 0; j < 4; ++j) {
        int i = i0 + j;
        if (i < n) {
            row_start[i] = excl;
            cursor[i] = excl;
            inv_deg[i] = 1.0f / (float)max(d[j], 1);
            excl += d[j];
        }
    }
}

__global__ void scatter_kernel(const int* __restrict__ idx, int* __restrict__ cursor,
                               int* __restrict__ sorted_src, int E) {
    int i = blockIdx.x * 256 + threadIdx.x;
    if (i < E) {
        int d = idx[E + i];
        int p = atomicAdd(&cursor[d], 1);
        sorted_src[p] = idx[i];
    }
}

// ---------------- mean aggregation (CSR gather-reduce) ----------------
// 32 threads per node, each owns a float4 column slice.
__global__ __launch_bounds__(256) void aggregate_kernel(
    const float* __restrict__ x, const int* __restrict__ row_start,
    const int* __restrict__ sorted_src, const float* __restrict__ inv_deg,
    float* __restrict__ aggr, int n) {
    int gid = blockIdx.x * 256 + threadIdx.x;
    int node = gid >> 5;
    if (node >= n) return;
    int q = (gid & 31) << 2;
    int beg = row_start[node];
    int end = row_start[node + 1];
    float4 acc = make_float4(0.f, 0.f, 0.f, 0.f);
    for (int e = beg; e < end; ++e) {
        int s = sorted_src[e];
        const float4 v = *(const float4*)(x + (size_t)s * NDIM + q);
        acc.x += v.x; acc.y += v.y; acc.z += v.z; acc.w += v.w;
    }
    float inv = inv_deg[node];
    acc.x *= inv; acc.y *= inv; acc.z *= inv; acc.w *= inv;
    *(float4*)(aggr + (size_t)node * NDIM + q) = acc;
}

// ------- fused layer GEMM v5: Y = Ag@Wl + X@Wr + b (+relu) -------
// R6 analysis: v4 was LDS-pipe-bound (6 ds_read_b128 = 72 LDS-cyc vs 32
// VALU-cyc per wave-k -> VALUBusy capped at 44%, measured 46%). v5 raises
// intensity: 128 threads, 64x128 tile, 8x8 acc/thread -> 8 b128 (96 LDS-cyc)
// per 128 FMA (64 VALU-cyc). No register prefetch (R5: spill -> 1 GB scratch).
// All LDS reads broadcast or 2-way (free). Tripwire: WRITE_SIZE must stay
// ~25 MB; if it balloons, v5 spilled.
__global__ __launch_bounds__(128, 2) void gemm_kernel(
    const float* Ag, const float* __restrict__ X,
    const float* __restrict__ Wl, const float* __restrict__ Wr,
    const float* __restrict__ bias, float* Y, int n, int do_relu) {
    __shared__ float Al[16][68];    // A^T [k][row], 272B stride
    __shared__ float Ar[16][68];
    __shared__ float Sl[16][128];   // W [k][col]
    __shared__ float Sr[16][128];
    const int tid = threadIdx.x;
    const int tx = tid & 15;    // col group: cols {tx*4..+3, 64+tx*4..+3}
    const int ty = tid >> 4;    // row group: rows ty*8 .. ty*8+7 (0..7)
    const int row0 = blockIdx.x * 64;
    float acc[8][8];
#pragma unroll
    for (int i = 0; i < 8; ++i)
#pragma unroll
        for (int j = 0; j < 8; ++j) acc[i][j] = 0.f;

    const int lrow = tid >> 1;          // 0..63
    const int lk = (tid & 1) << 3;      // 0 or 8
    const int wk = tid >> 5;            // 0..3
    const int wc = (tid & 31) << 2;     // 0..124
    const int arow = row0 + lrow;

    for (int k0 = 0; k0 < NDIM; k0 += 16) {
        float4 al0 = make_float4(0.f, 0.f, 0.f, 0.f), al1 = al0;
        float4 ar0 = al0, ar1 = al0;
        if (arow < n) {
            al0 = *(const float4*)(Ag + (size_t)arow * NDIM + k0 + lk);
            al1 = *(const float4*)(Ag + (size_t)arow * NDIM + k0 + lk + 4);
            ar0 = *(const float4*)(X + (size_t)arow * NDIM + k0 + lk);
            ar1 = *(const float4*)(X + (size_t)arow * NDIM + k0 + lk + 4);
        }
        const float4 wl0 = *(const float4*)(Wl + (size_t)(k0 + wk) * NDIM + wc);
        const float4 wl1 = *(const float4*)(Wl + (size_t)(k0 + wk + 4) * NDIM + wc);
        const float4 wl2 = *(const float4*)(Wl + (size_t)(k0 + wk + 8) * NDIM + wc);
        const float4 wl3 = *(const float4*)(Wl + (size_t)(k0 + wk + 12) * NDIM + wc);
        const float4 wr0 = *(const float4*)(Wr + (size_t)(k0 + wk) * NDIM + wc);
        const float4 wr1 = *(const float4*)(Wr + (size_t)(k0 + wk + 4) * NDIM + wc);
        const float4 wr2 = *(const float4*)(Wr + (size_t)(k0 + wk + 8) * NDIM + wc);
        const float4 wr3 = *(const float4*)(Wr + (size_t)(k0 + wk + 12) * NDIM + wc);
        __syncthreads();
        Al[lk + 0][lrow] = al0.x; Al[lk + 1][lrow] = al0.y;
        Al[lk + 2][lrow] = al0.z; Al[lk + 3][lrow] = al0.w;
        Al[lk + 4][lrow] = al1.x; Al[lk + 5][lrow] = al1.y;
        Al[lk + 6][lrow] = al1.z; Al[lk + 7][lrow] = al1.w;
        Ar[lk + 0][lrow] = ar0.x; Ar[lk + 1][lrow] = ar0.y;
        Ar[lk + 2][lrow] = ar0.z; Ar[lk + 3][lrow] = ar0.w;
        Ar[lk + 4][lrow] = ar1.x; Ar[lk + 5][lrow] = ar1.y;
        Ar[lk + 6][lrow] = ar1.z; Ar[lk + 7][lrow] = ar1.w;
        *(float4*)&Sl[wk][wc]      = wl0;
        *(float4*)&Sl[wk + 4][wc]  = wl1;
        *(float4*)&Sl[wk + 8][wc]  = wl2;
        *(float4*)&Sl[wk + 12][wc] = wl3;
        *(float4*)&Sr[wk][wc]      = wr0;
        *(float4*)&Sr[wk + 4][wc]  = wr1;
        *(float4*)&Sr[wk + 8][wc]  = wr2;
        *(float4*)&Sr[wk + 12][wc] = wr3;
        __syncthreads();
#pragma unroll 4
        for (int k = 0; k < 16; ++k) {
            const float4 a0 = *(const float4*)&Al[k][ty << 3];        // broadcast
            const float4 a1 = *(const float4*)&Al[k][(ty << 3) + 4];
            const float4 b0 = *(const float4*)&Ar[k][ty << 3];
            const float4 b1 = *(const float4*)&Ar[k][(ty << 3) + 4];
            const float4 l0 = *(const float4*)&Sl[k][tx << 2];        // 2-way (free)
            const float4 l1 = *(const float4*)&Sl[k][(tx << 2) + 64];
            const float4 r0 = *(const float4*)&Sr[k][tx << 2];
            const float4 r1 = *(const float4*)&Sr[k][(tx << 2) + 64];
            const float a8[8] = {a0.x, a0.y, a0.z, a0.w, a1.x, a1.y, a1.z, a1.w};
            const float x8[8] = {b0.x, b0.y, b0.z, b0.w, b1.x, b1.y, b1.z, b1.w};
            const float l8[8] = {l0.x, l0.y, l0.z, l0.w, l1.x, l1.y, l1.z, l1.w};
            const float r8[8] = {r0.x, r0.y, r0.z, r0.w, r1.x, r1.y, r1.z, r1.w};
#pragma unroll
            for (int i = 0; i < 8; ++i)
#pragma unroll
                for (int j = 0; j < 8; ++j)
                    acc[i][j] += a8[i] * l8[j] + x8[i] * r8[j];
        }
    }

    // epilogue: cols j0..3 -> tx*4, j4..7 -> 64+tx*4; rows ty*8+i
    const float4 bb0 = *(const float4*)(bias + (tx << 2));
    const float4 bb1 = *(const float4*)(bias + (tx << 2) + 64);
    const float bl4[4] = {bb0.x, bb0.y, bb0.z, bb0.w};
    const float bh4[4] = {bb1.x, bb1.y, bb1.z, bb1.w};
#pragma unroll
    for (int i = 0; i < 8; ++i) {
        const int r = row0 + (ty << 3) + i;
        if (r < n) {
            float lo[4], hi[4];
#pragma unroll
            for (int j = 0; j < 4; ++j) {
                lo[j] = acc[i][j] + bl4[j];
                hi[j] = acc[i][j + 4] + bh4[j];
                if (do_relu) { lo[j] = fmaxf(lo[j], 0.f); hi[j] = fmaxf(hi[j], 0.f); }
            }
            *(float4*)(Y + (size_t)r * NDIM + (tx << 2)) =
                make_float4(lo[0], lo[1], lo[2], lo[3]);
            *(float4*)(Y + (size_t)r * NDIM + (tx << 2) + 64) =
                make_float4(hi[0], hi[1], hi[2], hi[3]);
        }
    }
}

// ---------------- host launcher ----------------
extern "C" void kernel_launch(void* const* d_in, const int* in_sizes, int n_in,
                              void* d_out, int out_size, void* d_ws, size_t ws_size,
                              hipStream_t stream) {
    const float* x0   = (const float*)d_in[0];
    const int*   eraw = (const int*)d_in[1];
    const float* Wl   = (const float*)d_in[2];
    const float* bl   = (const float*)d_in[3];
    const float* Wr   = (const float*)d_in[4];
    float* out = (float*)d_out;

    const int N = in_sizes[0] / NDIM;   // 50000
    const int E = in_sizes[1] / 2;      // 600000

    auto align_up = [](size_t v) { return (v + 255) & ~(size_t)255; };
    char* p = (char*)d_ws;
    int* idx = (int*)p;                 p += align_up((size_t)2 * E * 4);
    int* deg = (int*)p;                 p += align_up((size_t)(N + 1) * 4);  // deg[N] is the flag
    int* flag = deg + N;
    int* row_start = (int*)p;           p += align_up((size_t)(N + 1) * 4);
    int* cursor = (int*)p;              p += align_up((size_t)N * 4);
    int* ssrc = (int*)p;                p += align_up((size_t)E * 4);
    float* invd = (float*)p;            p += align_up((size_t)N * 4);
    int* partials = (int*)p;            p += align_up((size_t)1024 * 4);
    float* buf0 = (float*)p;            p += align_up((size_t)N * NDIM * 4);
    float* buf1 = (float*)p;            p += align_up((size_t)N * NDIM * 4);

    const int nb = (N + 1023) / 1024;   // scan tiles

    hipMemsetAsync(deg, 0, (size_t)N * 4, stream);
    detect_kernel<<<1, 256, 0, stream>>>(eraw, flag, E);
    convert_kernel<<<(2 * E + 255) / 256, 256, 0, stream>>>(eraw, flag, idx, 2 * E);
    hist_kernel<<<(E + 255) / 256, 256, 0, stream>>>(idx, deg, E);
    deg_reduce_kernel<<<nb, 256, 0, stream>>>(deg, partials, N);
    scan_partials_kernel<<<1, 1024, 0, stream>>>(partials, nb, row_start, N);
    deg_downsweep_kernel<<<nb, 256, 0, stream>>>(deg, partials, row_start, cursor, invd, N);
    scatter_kernel<<<(E + 255) / 256, 256, 0, stream>>>(idx, cursor, ssrc, E);

    // Each gemm block reads and writes only its own 64-row band, with all
    // reads before the epilogue stores -> in-place (Y == Ag) is safe.
    const float* xin = x0;
    for (int l = 0; l < 5; ++l) {
        float* ab = (l & 1) ? buf1 : buf0;          // aggregation output
        aggregate_kernel<<<(N * 32 + 255) / 256, 256, 0, stream>>>(
            xin, row_start, ssrc, invd, ab, N);
        float* yo = (l == 4) ? out : ab;
        gemm_kernel<<<(N + 63) / 64, 128, 0, stream>>>(
            ab, xin, Wl + (size_t)l * NDIM * NDIM, Wr + (size_t)l * NDIM * NDIM,
            bl + (size_t)l * NDIM, yo, N, l < 4 ? 1 : 0);
        xin = yo;
    }
}

// Round 8
// 722.282 us; speedup vs baseline: 1.1626x; 1.1626x over previous
//
#include <hip/hip_runtime.h>

#define NDIM 128

// ---------------- edge-index normalization ----------------
// int64 edge_index => odd 32-bit words are 0; int32 => odd words are random
// node ids. ONE block samples 4096 edges; no global atomics (R2: full-E
// single-address atomic detection cost 108 us).
__global__ __launch_bounds__(256) void detect_kernel(
    const int* __restrict__ raw, int* __restrict__ flag, int E) {
    __shared__ int any_nz;
    if (threadIdx.x == 0) any_nz = 0;
    __syncthreads();
    int local = 0;
    const int samples = (E < 4096) ? E : 4096;
#pragma unroll
    for (int j = 0; j < 16; ++j) {
        int i = threadIdx.x * 16 + j;
        if (i < samples) local |= raw[2 * i + 1];
    }
    if (local) atomicOr(&any_nz, 1);   // LDS atomic, cheap
    __syncthreads();
    if (threadIdx.x == 0) *flag = any_nz;   // nonzero -> int32 layout
}

__global__ void convert_kernel(const int* __restrict__ raw, const int* __restrict__ flag,
                               int* __restrict__ idx, int total) {
    int i = blockIdx.x * 256 + threadIdx.x;
    if (i >= total) return;
    idx[i] = (*flag == 0) ? raw[2 * i] : raw[i];
}

// ---------------- CSR build (counting sort by dst) ----------------
__global__ void hist_kernel(const int* __restrict__ idx, int* __restrict__ deg, int E) {
    int i = blockIdx.x * 256 + threadIdx.x;
    if (i < E) atomicAdd(&deg[idx[E + i]], 1);  // dst row
}

// --- device-wide exclusive scan of deg, 3 kernels, tile = 1024 elements ---
__global__ __launch_bounds__(256) void deg_reduce_kernel(
    const int* __restrict__ deg, int* __restrict__ partials, int n) {
    const int base = blockIdx.x * 1024;
    const int tid = threadIdx.x;
    int s = 0;
#pragma unroll
    for (int j = 0; j < 4; ++j) {
        int i = base + tid * 4 + j;
        if (i < n) s += deg[i];
    }
#pragma unroll
    for (int off = 32; off; off >>= 1) s += __shfl_down(s, off);
    __shared__ int ws[4];
    if ((tid & 63) == 0) ws[tid >> 6] = s;
    __syncthreads();
    if (tid == 0) partials[blockIdx.x] = ws[0] + ws[1] + ws[2] + ws[3];
}

__global__ void scan_partials_kernel(int* __restrict__ partials, int nb,
                                     int* __restrict__ row_start, int n) {
    __shared__ int sh[1024];
    const int tid = threadIdx.x;  // 1024 threads
    int v = (tid < nb) ? partials[tid] : 0;
    sh[tid] = v;
    __syncthreads();
    for (int off = 1; off < 1024; off <<= 1) {
        int a = sh[tid];
        int b = (tid >= off) ? sh[tid - off] : 0;
        __syncthreads();
        sh[tid] = a + b;
        __syncthreads();
    }
    if (tid < nb) partials[tid] = (tid == 0) ? 0 : sh[tid - 1];  // exclusive block offset
    if (tid == 0) row_start[n] = sh[1023];                       // total edge count
}

__global__ __launch_bounds__(256) void deg_downsweep_kernel(
    const int* __restrict__ deg, const int* __restrict__ partials,
    int* __restrict__ row_start, int* __restrict__ cursor,
    float* __restrict__ inv_deg, int n) {
    const int base = blockIdx.x * 1024;
    const int tid = threadIdx.x;
    const int i0 = base + tid * 4;
    int d[4];
    int s = 0;
#pragma unroll
    for (int j = 0; j < 4; ++j) {
        int i = i0 + j;
        d[j] = (i < n) ? deg[i] : 0;
        s += d[j];
    }
    const int lane = tid & 63;
    int incl = s;
#pragma unroll
    for (int off = 1; off < 64; off <<= 1) {
        int t = __shfl_up(incl, off);
        if (lane >= off) incl += t;
    }
    __shared__ int wsum[4];
    if (lane == 63) wsum[tid >> 6] = incl;
    __syncthreads();
    int woff = 0;
    const int w = tid >> 6;
    for (int k = 0; k < w; ++k) woff += wsum[k];
    int excl = incl - s + woff + partials[blockIdx.x];
#pragma unroll
    for (int j = 0; j < 4; ++j) {
        int i = i0 + j;
        if (i < n) {
            row_start[i] = excl;
            cursor[i] = excl;
            inv_deg[i] = 1.0f / (float)max(d[j], 1);
            excl += d[j];
        }
    }
}

__global__ void scatter_kernel(const int* __restrict__ idx, int* __restrict__ cursor,
                               int* __restrict__ sorted_src, int E) {
    int i = blockIdx.x * 256 + threadIdx.x;
    if (i < E) {
        int d = idx[E + i];
        int p = atomicAdd(&cursor[d], 1);
        sorted_src[p] = idx[i];
    }
}

// ---------------- mean aggregation (CSR gather-reduce) ----------------
// 32 threads per node, each owns a float4 column slice.
__global__ __launch_bounds__(256) void aggregate_kernel(
    const float* __restrict__ x, const int* __restrict__ row_start,
    const int* __restrict__ sorted_src, const float* __restrict__ inv_deg,
    float* __restrict__ aggr, int n) {
    int gid = blockIdx.x * 256 + threadIdx.x;
    int node = gid >> 5;
    if (node >= n) return;
    int q = (gid & 31) << 2;
    int beg = row_start[node];
    int end = row_start[node + 1];
    float4 acc = make_float4(0.f, 0.f, 0.f, 0.f);
    for (int e = beg; e < end; ++e) {
        int s = sorted_src[e];
        const float4 v = *(const float4*)(x + (size_t)s * NDIM + q);
        acc.x += v.x; acc.y += v.y; acc.z += v.z; acc.w += v.w;
    }
    float inv = inv_deg[node];
    acc.x *= inv; acc.y *= inv; acc.z *= inv; acc.w *= inv;
    *(float4*)(aggr + (size_t)node * NDIM + q) = acc;
}

// ------- fused layer GEMM v6: Y = Ag@Wl + X@Wr + b (+relu) -------
// R7 analysis: constraint is resident-wave count, not LDS pipe (broadcast
// reads are cheap; VALUBusy tracked occupancy 46%@6.3w -> 35%@3.4w). v6:
// 64x64 tiles, grid (782,2)=1564 blocks (~6.1/CU), 256 thr, 4x4 acc
// (~45 VGPR, no spill), LDS 17.4 KB -> ~24 waves/CU (2x v4). Per-wave-k:
// LDS ~640B (~8 cyc) vs 32 FMA insts (16 CU-cyc) -> VALU-bound.
__global__ __launch_bounds__(256) void gemm_kernel(
    const float* __restrict__ Ag, const float* __restrict__ X,
    const float* __restrict__ Wl, const float* __restrict__ Wr,
    const float* __restrict__ bias, float* __restrict__ Y, int n, int do_relu) {
    __shared__ float Al[16][68];   // A^T [k][row], banks: scalar stores 2-way, reads disjoint
    __shared__ float Ar[16][68];
    __shared__ float Sl[16][68];   // W [k][col-local], pad 68 spreads store banks
    __shared__ float Sr[16][68];
    const int tid = threadIdx.x;
    const int tx = tid & 15;       // col group: cols col0 + tx*4 .. +3
    const int ty = tid >> 4;       // row group: rows ty*4 .. ty*4+3 (0..15)
    const int row0 = blockIdx.x * 64;
    const int col0 = blockIdx.y * 64;
    float acc[4][4];
#pragma unroll
    for (int i = 0; i < 4; ++i)
#pragma unroll
        for (int j = 0; j < 4; ++j) acc[i][j] = 0.f;

    const int lrow = tid >> 2;          // 0..63
    const int lk = (tid & 3) << 2;      // 0,4,8,12
    const int arow = row0 + lrow;
    const int wk = tid >> 4;            // 0..15
    const int wc = (tid & 15) << 2;     // 0..60

    for (int k0 = 0; k0 < NDIM; k0 += 16) {
        float4 a_l = make_float4(0.f, 0.f, 0.f, 0.f);
        float4 a_r = a_l;
        if (arow < n) {
            a_l = *(const float4*)(Ag + (size_t)arow * NDIM + k0 + lk);
            a_r = *(const float4*)(X + (size_t)arow * NDIM + k0 + lk);
        }
        const float4 wlv = *(const float4*)(Wl + (size_t)(k0 + wk) * NDIM + col0 + wc);
        const float4 wrv = *(const float4*)(Wr + (size_t)(k0 + wk) * NDIM + col0 + wc);
        __syncthreads();
        Al[lk + 0][lrow] = a_l.x; Al[lk + 1][lrow] = a_l.y;
        Al[lk + 2][lrow] = a_l.z; Al[lk + 3][lrow] = a_l.w;
        Ar[lk + 0][lrow] = a_r.x; Ar[lk + 1][lrow] = a_r.y;
        Ar[lk + 2][lrow] = a_r.z; Ar[lk + 3][lrow] = a_r.w;
        *(float4*)&Sl[wk][wc] = wlv;
        *(float4*)&Sr[wk][wc] = wrv;
        __syncthreads();
#pragma unroll 4
        for (int k = 0; k < 16; ++k) {
            const float4 av = *(const float4*)&Al[k][ty << 2];  // 4-addr broadcast
            const float4 bv = *(const float4*)&Ar[k][ty << 2];
            const float4 lv = *(const float4*)&Sl[k][tx << 2];  // 16-addr, <=2-way
            const float4 rv = *(const float4*)&Sr[k][tx << 2];
            const float a4[4] = {av.x, av.y, av.z, av.w};
            const float b4[4] = {bv.x, bv.y, bv.z, bv.w};
            const float l4[4] = {lv.x, lv.y, lv.z, lv.w};
            const float r4[4] = {rv.x, rv.y, rv.z, rv.w};
#pragma unroll
            for (int i = 0; i < 4; ++i)
#pragma unroll
                for (int j = 0; j < 4; ++j)
                    acc[i][j] += a4[i] * l4[j] + b4[i] * r4[j];
        }
    }

    const float4 bb = *(const float4*)(bias + col0 + (tx << 2));
    const float b4[4] = {bb.x, bb.y, bb.z, bb.w};
#pragma unroll
    for (int i = 0; i < 4; ++i) {
        const int r = row0 + (ty << 2) + i;
        if (r < n) {
            float o[4];
#pragma unroll
            for (int j = 0; j < 4; ++j) {
                o[j] = acc[i][j] + b4[j];
                if (do_relu) o[j] = fmaxf(o[j], 0.f);
            }
            *(float4*)(Y + (size_t)r * NDIM + col0 + (tx << 2)) =
                make_float4(o[0], o[1], o[2], o[3]);
        }
    }
}

// ---------------- host launcher ----------------
extern "C" void kernel_launch(void* const* d_in, const int* in_sizes, int n_in,
                              void* d_out, int out_size, void* d_ws, size_t ws_size,
                              hipStream_t stream) {
    const float* x0   = (const float*)d_in[0];
    const int*   eraw = (const int*)d_in[1];
    const float* Wl   = (const float*)d_in[2];
    const float* bl   = (const float*)d_in[3];
    const float* Wr   = (const float*)d_in[4];
    float* out = (float*)d_out;

    const int N = in_sizes[0] / NDIM;   // 50000
    const int E = in_sizes[1] / 2;      // 600000

    auto align_up = [](size_t v) { return (v + 255) & ~(size_t)255; };
    char* p = (char*)d_ws;
    int* idx = (int*)p;                 p += align_up((size_t)2 * E * 4);
    int* deg = (int*)p;                 p += align_up((size_t)(N + 1) * 4);  // deg[N] is the flag
    int* flag = deg + N;
    int* row_start = (int*)p;           p += align_up((size_t)(N + 1) * 4);
    int* cursor = (int*)p;              p += align_up((size_t)N * 4);
    int* ssrc = (int*)p;                p += align_up((size_t)E * 4);
    float* invd = (float*)p;            p += align_up((size_t)N * 4);
    int* partials = (int*)p;            p += align_up((size_t)1024 * 4);
    float* buf0 = (float*)p;            p += align_up((size_t)N * NDIM * 4);
    float* buf1 = (float*)p;            p += align_up((size_t)N * NDIM * 4);

    const int nb = (N + 1023) / 1024;   // scan tiles

    hipMemsetAsync(deg, 0, (size_t)N * 4, stream);
    detect_kernel<<<1, 256, 0, stream>>>(eraw, flag, E);
    convert_kernel<<<(2 * E + 255) / 256, 256, 0, stream>>>(eraw, flag, idx, 2 * E);
    hist_kernel<<<(E + 255) / 256, 256, 0, stream>>>(idx, deg, E);
    deg_reduce_kernel<<<nb, 256, 0, stream>>>(deg, partials, N);
    scan_partials_kernel<<<1, 1024, 0, stream>>>(partials, nb, row_start, N);
    deg_downsweep_kernel<<<nb, 256, 0, stream>>>(deg, partials, row_start, cursor, invd, N);
    scatter_kernel<<<(E + 255) / 256, 256, 0, stream>>>(idx, cursor, ssrc, E);

    // Column-split gemm blocks cover only half of each row's columns, so
    // gemm output must not alias Ag or X. Rotate gemm outputs through
    // {out, buf1}; aggregate always writes buf0. y: l0->out, l1->buf1,
    // l2->out, l3->buf1, l4->out.
    const int gm = (N + 63) / 64;
    const float* xin = x0;
    for (int l = 0; l < 5; ++l) {
        aggregate_kernel<<<(N * 32 + 255) / 256, 256, 0, stream>>>(
            xin, row_start, ssrc, invd, buf0, N);
        float* yo = (l & 1) ? buf1 : out;
        gemm_kernel<<<dim3(gm, 2), 256, 0, stream>>>(
            buf0, xin, Wl + (size_t)l * NDIM * NDIM, Wr + (size_t)l * NDIM * NDIM,
            bl + (size_t)l * NDIM, yo, N, l < 4 ? 1 : 0);
        xin = yo;
    }
}

// Round 9
// 571.579 us; speedup vs baseline: 1.4691x; 1.2637x over previous
//
#include <hip/hip_runtime.h>

#define NDIM 128

typedef __attribute__((ext_vector_type(8))) short s16x8;
typedef __attribute__((ext_vector_type(4))) float f32x4;

// fp32 -> bf16 (RNE) and back, bit-level (no header type friction)
__device__ __forceinline__ unsigned short f2bf(float f) {
    unsigned u = __float_as_uint(f);
    u += 0x7FFFu + ((u >> 16) & 1u);
    return (unsigned short)(u >> 16);
}
__device__ __forceinline__ float bf2f(unsigned short h) {
    return __uint_as_float((unsigned)h << 16);
}

// ---------------- edge-index normalization ----------------
__global__ __launch_bounds__(256) void detect_kernel(
    const int* __restrict__ raw, int* __restrict__ flag, int E) {
    __shared__ int any_nz;
    if (threadIdx.x == 0) any_nz = 0;
    __syncthreads();
    int local = 0;
    const int samples = (E < 4096) ? E : 4096;
#pragma unroll
    for (int j = 0; j < 16; ++j) {
        int i = threadIdx.x * 16 + j;
        if (i < samples) local |= raw[2 * i + 1];
    }
    if (local) atomicOr(&any_nz, 1);
    __syncthreads();
    if (threadIdx.x == 0) *flag = any_nz;   // nonzero -> int32 layout
}

__global__ void convert_kernel(const int* __restrict__ raw, const int* __restrict__ flag,
                               int* __restrict__ idx, int total) {
    int i = blockIdx.x * 256 + threadIdx.x;
    if (i >= total) return;
    idx[i] = (*flag == 0) ? raw[2 * i] : raw[i];
}

// ---------------- CSR build (counting sort by dst) ----------------
__global__ void hist_kernel(const int* __restrict__ idx, int* __restrict__ deg, int E) {
    int i = blockIdx.x * 256 + threadIdx.x;
    if (i < E) atomicAdd(&deg[idx[E + i]], 1);
}

__global__ __launch_bounds__(256) void deg_reduce_kernel(
    const int* __restrict__ deg, int* __restrict__ partials, int n) {
    const int base = blockIdx.x * 1024;
    const int tid = threadIdx.x;
    int s = 0;
#pragma unroll
    for (int j = 0; j < 4; ++j) {
        int i = base + tid * 4 + j;
        if (i < n) s += deg[i];
    }
#pragma unroll
    for (int off = 32; off; off >>= 1) s += __shfl_down(s, off);
    __shared__ int ws[4];
    if ((tid & 63) == 0) ws[tid >> 6] = s;
    __syncthreads();
    if (tid == 0) partials[blockIdx.x] = ws[0] + ws[1] + ws[2] + ws[3];
}

__global__ void scan_partials_kernel(int* __restrict__ partials, int nb,
                                     int* __restrict__ row_start, int n) {
    __shared__ int sh[1024];
    const int tid = threadIdx.x;
    int v = (tid < nb) ? partials[tid] : 0;
    sh[tid] = v;
    __syncthreads();
    for (int off = 1; off < 1024; off <<= 1) {
        int a = sh[tid];
        int b = (tid >= off) ? sh[tid - off] : 0;
        __syncthreads();
        sh[tid] = a + b;
        __syncthreads();
    }
    if (tid < nb) partials[tid] = (tid == 0) ? 0 : sh[tid - 1];
    if (tid == 0) row_start[n] = sh[1023];
}

__global__ __launch_bounds__(256) void deg_downsweep_kernel(
    const int* __restrict__ deg, const int* __restrict__ partials,
    int* __restrict__ row_start, int* __restrict__ cursor,
    float* __restrict__ inv_deg, int n) {
    const int base = blockIdx.x * 1024;
    const int tid = threadIdx.x;
    const int i0 = base + tid * 4;
    int d[4];
    int s = 0;
#pragma unroll
    for (int j = 0; j < 4; ++j) {
        int i = i0 + j;
        d[j] = (i < n) ? deg[i] : 0;
        s += d[j];
    }
    const int lane = tid & 63;
    int incl = s;
#pragma unroll
    for (int off = 1; off < 64; off <<= 1) {
        int t = __shfl_up(incl, off);
        if (lane >= off) incl += t;
    }
    __shared__ int wsum[4];
    if (lane == 63) wsum[tid >> 6] = incl;
    __syncthreads();
    int woff = 0;
    const int w = tid >> 6;
    for (int k = 0; k < w; ++k) woff += wsum[k];
    int excl = incl - s + woff + partials[blockIdx.x];
#pragma unroll
    for (int j = 0; j < 4; ++j) {
        int i = i0 + j;
        if (i < n) {
            row_start[i] = excl;
            cursor[i] = excl;
            inv_deg[i] = 1.0f / (float)max(d[j], 1);
            excl += d[j];
        }
    }
}

__global__ void scatter_kernel(const int* __restrict__ idx, int* __restrict__ cursor,
                               int* __restrict__ sorted_src, int E) {
    int i = blockIdx.x * 256 + threadIdx.x;
    if (i < E) {
        int d = idx[E + i];
        int p = atomicAdd(&cursor[d], 1);
        sorted_src[p] = idx[i];
    }
}

// ---------------- mean aggregation (CSR gather-reduce) ----------------
__global__ __launch_bounds__(256) void aggregate_kernel(
    const float* __restrict__ x, const int* __restrict__ row_start,
    const int* __restrict__ sorted_src, const float* __restrict__ inv_deg,
    float* __restrict__ aggr, int n) {
    int gid = blockIdx.x * 256 + threadIdx.x;
    int node = gid >> 5;
    if (node >= n) return;
    int q = (gid & 31) << 2;
    int beg = row_start[node];
    int end = row_start[node + 1];
    float4 acc = make_float4(0.f, 0.f, 0.f, 0.f);
    for (int e = beg; e < end; ++e) {
        int s = sorted_src[e];
        const float4 v = *(const float4*)(x + (size_t)s * NDIM + q);
        acc.x += v.x; acc.y += v.y; acc.z += v.z; acc.w += v.w;
    }
    float inv = inv_deg[node];
    acc.x *= inv; acc.y *= inv; acc.z *= inv; acc.w *= inv;
    *(float4*)(aggr + (size_t)node * NDIM + q) = acc;
}

// ---- pre-split + transpose W: Wl/Wr [5][128k][128n] fp32 ->
//      wth/wtl [mat(2)][5][n=128][k=128] bf16 (hi, lo) ----
__global__ __launch_bounds__(256) void presplit_kernel(
    const float* __restrict__ Wl, const float* __restrict__ Wr,
    short* __restrict__ wth, short* __restrict__ wtl, int total) {
    int idx = blockIdx.x * 256 + threadIdx.x;
    if (idx >= total) return;
    int k = idx & 127;
    int nn = (idx >> 7) & 127;
    int lm = idx >> 14;             // mat*5 + l, 0..9
    int mat = lm / 5;
    int l = lm % 5;
    const float* src = mat ? Wr : Wl;
    float v = src[(size_t)l * 16384 + (size_t)k * 128 + nn];   // transpose read
    unsigned short h = f2bf(v);
    unsigned short lo = f2bf(v - bf2f(h));
    wth[idx] = (short)h;
    wtl[idx] = (short)lo;
}

// ------- GEMM v7 (MFMA split-bf16): Y = Ag@Wl + X@Wr + b (+relu) -------
// fp32 via 3 bf16 products per matmul: Ah@Wh + Ah@Wl + Al@Wh (Al@Wl ~2^-18
// dropped). 256 thr / 4 waves, 64x128 tile, wave = 32 rows x 64 cols =
// 2x4 C-frags. K-chunks of 32. LDS 61.4 KB -> 2 blocks/CU.
// MFMA layouts [measured m89/m91/m120]: A: m=lane&15, k=quad*8+j;
// B: n=lane&15, k=quad*8+j; C/D: col=lane&15, row=quad*4+reg.
// LDS row stride 40 shorts (80 B): frag reads 2-way bank alias (free).
// Spill tripwire: WRITE_SIZE must stay ~25 MB (R5: 1 GB = spilled).
__global__ __launch_bounds__(256, 2) void gemm_kernel(
    const float* __restrict__ Ag, const float* __restrict__ X,
    const short* __restrict__ Wlh, const short* __restrict__ Wll,
    const short* __restrict__ Wrh, const short* __restrict__ Wrl,
    const float* __restrict__ bias, float* __restrict__ Y, int n, int do_relu) {
    __shared__ short sAgh[64][40], sAgl[64][40], sXh[64][40], sXl[64][40];
    __shared__ short sWlh[128][40], sWll[128][40], sWrh[128][40], sWrl[128][40];
    const int tid = threadIdx.x;
    const int lane = tid & 63;
    const int wave = tid >> 6;
    const int ln15 = lane & 15;
    const int quad = lane >> 4;
    const int row0 = blockIdx.x * 64;
    const int wr0 = (wave & 1) * 32;     // wave's row offset in tile
    const int wc0 = (wave >> 1) * 64;    // wave's col offset

    f32x4 acc[2][4];
#pragma unroll
    for (int i = 0; i < 2; ++i)
#pragma unroll
        for (int j = 0; j < 4; ++j) acc[i][j] = (f32x4)(0.f);

    // A staging assignment: thread -> (mat, row, k-half)
    const int sm = tid >> 7;            // 0=Ag, 1=X
    const int srow = (tid >> 1) & 63;
    const int sh = tid & 1;             // 16-float half of the 32-k chunk
    int arow = row0 + srow;
    if (arow >= n) arow = n - 1;
    const float* asrc = (sm ? X : Ag) + (size_t)arow * NDIM + sh * 16;
    short* dsthi = (sm ? &sXh[0][0] : &sAgh[0][0]) + srow * 40 + sh * 16;
    short* dstlo = (sm ? &sXl[0][0] : &sAgl[0][0]) + srow * 40 + sh * 16;

    // W staging assignment: 2 slots per thread, slot -> (wmat, wrow)
    const int wi0 = tid;                // slot 0
    const int wi1 = tid + 256;          // slot 1
    const int wm0 = wi0 >> 7, wrow0s = wi0 & 127;
    const int wm1 = wi1 >> 7, wrow1s = wi1 & 127;
    const short* wsrc0 = (wm0 == 0 ? Wlh : wm0 == 1 ? Wll : wm0 == 2 ? Wrh : Wrl) + wrow0s * 128;
    const short* wsrc1 = (wm1 == 0 ? Wlh : wm1 == 1 ? Wll : wm1 == 2 ? Wrh : Wrl) + wrow1s * 128;
    short* wdst0 = (wm0 == 0 ? &sWlh[0][0] : wm0 == 1 ? &sWll[0][0] : wm0 == 2 ? &sWrh[0][0] : &sWrl[0][0]) + wrow0s * 40;
    short* wdst1 = (wm1 == 0 ? &sWlh[0][0] : wm1 == 1 ? &sWll[0][0] : wm1 == 2 ? &sWrh[0][0] : &sWrl[0][0]) + wrow1s * 40;

    for (int k0 = 0; k0 < NDIM; k0 += 32) {
        // global reads for this chunk
        float4 f0 = *(const float4*)(asrc + k0);
        float4 f1 = *(const float4*)(asrc + k0 + 4);
        float4 f2 = *(const float4*)(asrc + k0 + 8);
        float4 f3 = *(const float4*)(asrc + k0 + 12);
        int4 wv0[2], wv1[2];
#pragma unroll
        for (int j = 0; j < 2; ++j) {
            wv0[j] = *(const int4*)(wsrc0 + k0 + j * 8);
            wv1[j] = *(const int4*)(wsrc1 + k0 + j * 8);
        }
        int4 wv0b[2], wv1b[2];
#pragma unroll
        for (int j = 0; j < 2; ++j) {
            wv0b[j] = *(const int4*)(wsrc0 + k0 + 16 + j * 8);
            wv1b[j] = *(const int4*)(wsrc1 + k0 + 16 + j * 8);
        }
        __syncthreads();
        // A split + LDS write
        {
            float vals[16] = {f0.x, f0.y, f0.z, f0.w, f1.x, f1.y, f1.z, f1.w,
                              f2.x, f2.y, f2.z, f2.w, f3.x, f3.y, f3.z, f3.w};
#pragma unroll
            for (int j = 0; j < 4; ++j) {
                unsigned short h[4], l[4];
#pragma unroll
                for (int m = 0; m < 4; ++m) {
                    float v = vals[j * 4 + m];
                    h[m] = f2bf(v);
                    l[m] = f2bf(v - bf2f(h[m]));
                }
                int2 wh = make_int2((int)(h[0] | ((unsigned)h[1] << 16)),
                                    (int)(h[2] | ((unsigned)h[3] << 16)));
                int2 wl = make_int2((int)(l[0] | ((unsigned)l[1] << 16)),
                                    (int)(l[2] | ((unsigned)l[3] << 16)));
                *(int2*)(dsthi + j * 4) = wh;
                *(int2*)(dstlo + j * 4) = wl;
            }
        }
        // W LDS write (copy, already bf16)
#pragma unroll
        for (int j = 0; j < 2; ++j) {
            ((int2*)(wdst0 + j * 8))[0] = make_int2(wv0[j].x, wv0[j].y);
            ((int2*)(wdst0 + j * 8))[1] = make_int2(wv0[j].z, wv0[j].w);
            ((int2*)(wdst1 + j * 8))[0] = make_int2(wv1[j].x, wv1[j].y);
            ((int2*)(wdst1 + j * 8))[1] = make_int2(wv1[j].z, wv1[j].w);
            ((int2*)(wdst0 + 16 + j * 8))[0] = make_int2(wv0b[j].x, wv0b[j].y);
            ((int2*)(wdst0 + 16 + j * 8))[1] = make_int2(wv0b[j].z, wv0b[j].w);
            ((int2*)(wdst1 + 16 + j * 8))[0] = make_int2(wv1b[j].x, wv1b[j].y);
            ((int2*)(wdst1 + 16 + j * 8))[1] = make_int2(wv1b[j].z, wv1b[j].w);
        }
        __syncthreads();

        // A fragments for this wave's 2 row-tiles
        s16x8 fAgh[2], fAgl[2], fXh[2], fXl[2];
#pragma unroll
        for (int rt = 0; rt < 2; ++rt) {
            const int r = wr0 + rt * 16 + ln15;
            const short* p;
            p = &sAgh[r][quad * 8];
            ((int2*)&fAgh[rt])[0] = *(const int2*)p; ((int2*)&fAgh[rt])[1] = *(const int2*)(p + 4);
            p = &sAgl[r][quad * 8];
            ((int2*)&fAgl[rt])[0] = *(const int2*)p; ((int2*)&fAgl[rt])[1] = *(const int2*)(p + 4);
            p = &sXh[r][quad * 8];
            ((int2*)&fXh[rt])[0] = *(const int2*)p; ((int2*)&fXh[rt])[1] = *(const int2*)(p + 4);
            p = &sXl[r][quad * 8];
            ((int2*)&fXl[rt])[0] = *(const int2*)p; ((int2*)&fXl[rt])[1] = *(const int2*)(p + 4);
        }
#pragma unroll
        for (int ct = 0; ct < 4; ++ct) {
            const int c = wc0 + ct * 16 + ln15;
            s16x8 blh, bll, brh, brl;
            const short* p;
            p = &sWlh[c][quad * 8];
            ((int2*)&blh)[0] = *(const int2*)p; ((int2*)&blh)[1] = *(const int2*)(p + 4);
            p = &sWll[c][quad * 8];
            ((int2*)&bll)[0] = *(const int2*)p; ((int2*)&bll)[1] = *(const int2*)(p + 4);
            p = &sWrh[c][quad * 8];
            ((int2*)&brh)[0] = *(const int2*)p; ((int2*)&brh)[1] = *(const int2*)(p + 4);
            p = &sWrl[c][quad * 8];
            ((int2*)&brl)[0] = *(const int2*)p; ((int2*)&brl)[1] = *(const int2*)(p + 4);
#pragma unroll
            for (int rt = 0; rt < 2; ++rt) {
                acc[rt][ct] = __builtin_amdgcn_mfma_f32_16x16x32_bf16(fAgh[rt], blh, acc[rt][ct], 0, 0, 0);
                acc[rt][ct] = __builtin_amdgcn_mfma_f32_16x16x32_bf16(fAgh[rt], bll, acc[rt][ct], 0, 0, 0);
                acc[rt][ct] = __builtin_amdgcn_mfma_f32_16x16x32_bf16(fAgl[rt], blh, acc[rt][ct], 0, 0, 0);
                acc[rt][ct] = __builtin_amdgcn_mfma_f32_16x16x32_bf16(fXh[rt], brh, acc[rt][ct], 0, 0, 0);
                acc[rt][ct] = __builtin_amdgcn_mfma_f32_16x16x32_bf16(fXh[rt], brl, acc[rt][ct], 0, 0, 0);
                acc[rt][ct] = __builtin_amdgcn_mfma_f32_16x16x32_bf16(fXl[rt], brh, acc[rt][ct], 0, 0, 0);
            }
        }
    }

    // epilogue: C/D layout col=lane&15, row=quad*4+reg [m89]
#pragma unroll
    for (int rt = 0; rt < 2; ++rt) {
#pragma unroll
        for (int ct = 0; ct < 4; ++ct) {
            const int col = wc0 + ct * 16 + ln15;
            const float bv = bias[col];
#pragma unroll
            for (int r = 0; r < 4; ++r) {
                const int grow = row0 + wr0 + rt * 16 + quad * 4 + r;
                if (grow < n) {
                    float v = acc[rt][ct][r] + bv;
                    if (do_relu) v = fmaxf(v, 0.f);
                    Y[(size_t)grow * NDIM + col] = v;
                }
            }
        }
    }
}

// ---------------- host launcher ----------------
extern "C" void kernel_launch(void* const* d_in, const int* in_sizes, int n_in,
                              void* d_out, int out_size, void* d_ws, size_t ws_size,
                              hipStream_t stream) {
    const float* x0   = (const float*)d_in[0];
    const int*   eraw = (const int*)d_in[1];
    const float* Wl   = (const float*)d_in[2];
    const float* bl   = (const float*)d_in[3];
    const float* Wr   = (const float*)d_in[4];
    float* out = (float*)d_out;

    const int N = in_sizes[0] / NDIM;   // 50000
    const int E = in_sizes[1] / 2;      // 600000

    auto align_up = [](size_t v) { return (v + 255) & ~(size_t)255; };
    char* p = (char*)d_ws;
    int* idx = (int*)p;                 p += align_up((size_t)2 * E * 4);
    int* deg = (int*)p;                 p += align_up((size_t)(N + 1) * 4);
    int* flag = deg + N;
    int* row_start = (int*)p;           p += align_up((size_t)(N + 1) * 4);
    int* cursor = (int*)p;              p += align_up((size_t)N * 4);
    int* ssrc = (int*)p;                p += align_up((size_t)E * 4);
    float* invd = (float*)p;            p += align_up((size_t)N * 4);
    int* partials = (int*)p;            p += align_up((size_t)1024 * 4);
    short* wth = (short*)p;             p += align_up((size_t)163840 * 2);
    short* wtl = (short*)p;             p += align_up((size_t)163840 * 2);
    float* buf0 = (float*)p;            p += align_up((size_t)N * NDIM * 4);
    float* buf1 = (float*)p;            p += align_up((size_t)N * NDIM * 4);

    const int nb = (N + 1023) / 1024;

    hipMemsetAsync(deg, 0, (size_t)N * 4, stream);
    detect_kernel<<<1, 256, 0, stream>>>(eraw, flag, E);
    convert_kernel<<<(2 * E + 255) / 256, 256, 0, stream>>>(eraw, flag, idx, 2 * E);
    hist_kernel<<<(E + 255) / 256, 256, 0, stream>>>(idx, deg, E);
    deg_reduce_kernel<<<nb, 256, 0, stream>>>(deg, partials, N);
    scan_partials_kernel<<<1, 1024, 0, stream>>>(partials, nb, row_start, N);
    deg_downsweep_kernel<<<nb, 256, 0, stream>>>(deg, partials, row_start, cursor, invd, N);
    scatter_kernel<<<(E + 255) / 256, 256, 0, stream>>>(idx, cursor, ssrc, E);
    presplit_kernel<<<640, 256, 0, stream>>>(Wl, Wr, wth, wtl, 163840);

    // Full-width 64-row-band gemm: all reads precede epilogue stores ->
    // in-place (Y == Ag) is safe (v4-verified launcher pattern).
    const float* xin = x0;
    for (int l = 0; l < 5; ++l) {
        float* ab = (l & 1) ? buf1 : buf0;
        aggregate_kernel<<<(N * 32 + 255) / 256, 256, 0, stream>>>(
            xin, row_start, ssrc, invd, ab, N);
        float* yo = (l == 4) ? out : ab;
        const short* wlh = wth + (size_t)l * 16384;
        const short* wll = wtl + (size_t)l * 16384;
        const short* wrh = wth + (size_t)(5 + l) * 16384;
        const short* wrl = wtl + (size_t)(5 + l) * 16384;
        gemm_kernel<<<(N + 63) / 64, 256, 0, stream>>>(
            ab, xin, wlh, wll, wrh, wrl,
            bl + (size_t)l * NDIM, yo, N, l < 4 ? 1 : 0);
        xin = yo;
    }
}

// Round 10
// 527.721 us; speedup vs baseline: 1.5912x; 1.0831x over previous
//
#include <hip/hip_runtime.h>

#define NDIM 128

typedef __attribute__((ext_vector_type(8))) short s16x8;
typedef __attribute__((ext_vector_type(4))) float f32x4;

// fp32 -> bf16 (RNE) and back, bit-level (no header type friction)
__device__ __forceinline__ unsigned short f2bf(float f) {
    unsigned u = __float_as_uint(f);
    u += 0x7FFFu + ((u >> 16) & 1u);
    return (unsigned short)(u >> 16);
}
__device__ __forceinline__ float bf2f(unsigned short h) {
    return __uint_as_float((unsigned)h << 16);
}

// ---------------- edge-index normalization ----------------
__global__ __launch_bounds__(256) void detect_kernel(
    const int* __restrict__ raw, int* __restrict__ flag, int E) {
    __shared__ int any_nz;
    if (threadIdx.x == 0) any_nz = 0;
    __syncthreads();
    int local = 0;
    const int samples = (E < 4096) ? E : 4096;
#pragma unroll
    for (int j = 0; j < 16; ++j) {
        int i = threadIdx.x * 16 + j;
        if (i < samples) local |= raw[2 * i + 1];
    }
    if (local) atomicOr(&any_nz, 1);
    __syncthreads();
    if (threadIdx.x == 0) *flag = any_nz;   // nonzero -> int32 layout
}

__global__ void convert_kernel(const int* __restrict__ raw, const int* __restrict__ flag,
                               int* __restrict__ idx, int total) {
    int i = blockIdx.x * 256 + threadIdx.x;
    if (i >= total) return;
    idx[i] = (*flag == 0) ? raw[2 * i] : raw[i];
}

// ---------------- CSR build (counting sort by dst) ----------------
__global__ void hist_kernel(const int* __restrict__ idx, int* __restrict__ deg, int E) {
    int i = blockIdx.x * 256 + threadIdx.x;
    if (i < E) atomicAdd(&deg[idx[E + i]], 1);
}

__global__ __launch_bounds__(256) void deg_reduce_kernel(
    const int* __restrict__ deg, int* __restrict__ partials, int n) {
    const int base = blockIdx.x * 1024;
    const int tid = threadIdx.x;
    int s = 0;
#pragma unroll
    for (int j = 0; j < 4; ++j) {
        int i = base + tid * 4 + j;
        if (i < n) s += deg[i];
    }
#pragma unroll
    for (int off = 32; off; off >>= 1) s += __shfl_down(s, off);
    __shared__ int ws[4];
    if ((tid & 63) == 0) ws[tid >> 6] = s;
    __syncthreads();
    if (tid == 0) partials[blockIdx.x] = ws[0] + ws[1] + ws[2] + ws[3];
}

__global__ void scan_partials_kernel(int* __restrict__ partials, int nb,
                                     int* __restrict__ row_start, int n) {
    __shared__ int sh[1024];
    const int tid = threadIdx.x;
    int v = (tid < nb) ? partials[tid] : 0;
    sh[tid] = v;
    __syncthreads();
    for (int off = 1; off < 1024; off <<= 1) {
        int a = sh[tid];
        int b = (tid >= off) ? sh[tid - off] : 0;
        __syncthreads();
        sh[tid] = a + b;
        __syncthreads();
    }
    if (tid < nb) partials[tid] = (tid == 0) ? 0 : sh[tid - 1];
    if (tid == 0) row_start[n] = sh[1023];
}

__global__ __launch_bounds__(256) void deg_downsweep_kernel(
    const int* __restrict__ deg, const int* __restrict__ partials,
    int* __restrict__ row_start, int* __restrict__ cursor,
    float* __restrict__ inv_deg, int n) {
    const int base = blockIdx.x * 1024;
    const int tid = threadIdx.x;
    const int i0 = base + tid * 4;
    int d[4];
    int s = 0;
#pragma unroll
    for (int j = 0; j < 4; ++j) {
        int i = i0 + j;
        d[j] = (i < n) ? deg[i] : 0;
        s += d[j];
    }
    const int lane = tid & 63;
    int incl = s;
#pragma unroll
    for (int off = 1; off < 64; off <<= 1) {
        int t = __shfl_up(incl, off);
        if (lane >= off) incl += t;
    }
    __shared__ int wsum[4];
    if (lane == 63) wsum[tid >> 6] = incl;
    __syncthreads();
    int woff = 0;
    const int w = tid >> 6;
    for (int k = 0; k < w; ++k) woff += wsum[k];
    int excl = incl - s + woff + partials[blockIdx.x];
#pragma unroll
    for (int j = 0; j < 4; ++j) {
        int i = i0 + j;
        if (i < n) {
            row_start[i] = excl;
            cursor[i] = excl;
            inv_deg[i] = 1.0f / (float)max(d[j], 1);
            excl += d[j];
        }
    }
}

__global__ void scatter_kernel(const int* __restrict__ idx, int* __restrict__ cursor,
                               int* __restrict__ sorted_src, int E) {
    int i = blockIdx.x * 256 + threadIdx.x;
    if (i < E) {
        int d = idx[E + i];
        int p = atomicAdd(&cursor[d], 1);
        sorted_src[p] = idx[i];
    }
}

// ---------------- mean aggregation v2 (CSR gather, edge-chunked MLP) -------
// R9 analysis: v1's serial edge loop had ~1 outstanding gather/wave ->
// 3.1 TB/s latency-bound plateau (51 us). v2 chunks 4 edges: 4 index loads
// + 4 independent float4 row-gathers in flight before any accumulate.
__global__ __launch_bounds__(256) void aggregate_kernel(
    const float* __restrict__ x, const int* __restrict__ row_start,
    const int* __restrict__ sorted_src, const float* __restrict__ inv_deg,
    float* __restrict__ aggr, int n) {
    int gid = blockIdx.x * 256 + threadIdx.x;
    int node = gid >> 5;
    if (node >= n) return;
    int q = (gid & 31) << 2;
    int beg = row_start[node];
    int end = row_start[node + 1];
    float4 acc = make_float4(0.f, 0.f, 0.f, 0.f);
    int e = beg;
    for (; e + 4 <= end; e += 4) {
        const int s0 = sorted_src[e + 0];
        const int s1 = sorted_src[e + 1];
        const int s2 = sorted_src[e + 2];
        const int s3 = sorted_src[e + 3];
        const float4 v0 = *(const float4*)(x + (size_t)s0 * NDIM + q);
        const float4 v1 = *(const float4*)(x + (size_t)s1 * NDIM + q);
        const float4 v2 = *(const float4*)(x + (size_t)s2 * NDIM + q);
        const float4 v3 = *(const float4*)(x + (size_t)s3 * NDIM + q);
        acc.x += (v0.x + v1.x) + (v2.x + v3.x);
        acc.y += (v0.y + v1.y) + (v2.y + v3.y);
        acc.z += (v0.z + v1.z) + (v2.z + v3.z);
        acc.w += (v0.w + v1.w) + (v2.w + v3.w);
    }
    for (; e < end; ++e) {
        const int s = sorted_src[e];
        const float4 v = *(const float4*)(x + (size_t)s * NDIM + q);
        acc.x += v.x; acc.y += v.y; acc.z += v.z; acc.w += v.w;
    }
    float inv = inv_deg[node];
    acc.x *= inv; acc.y *= inv; acc.z *= inv; acc.w *= inv;
    *(float4*)(aggr + (size_t)node * NDIM + q) = acc;
}

// ---- pre-split + transpose W: Wl/Wr [5][128k][128n] fp32 ->
//      wth/wtl [mat(2)][5][n=128][k=128] bf16 (hi, lo) ----
__global__ __launch_bounds__(256) void presplit_kernel(
    const float* __restrict__ Wl, const float* __restrict__ Wr,
    short* __restrict__ wth, short* __restrict__ wtl, int total) {
    int idx = blockIdx.x * 256 + threadIdx.x;
    if (idx >= total) return;
    int k = idx & 127;
    int nn = (idx >> 7) & 127;
    int lm = idx >> 14;             // mat*5 + l, 0..9
    int mat = lm / 5;
    int l = lm % 5;
    const float* src = mat ? Wr : Wl;
    float v = src[(size_t)l * 16384 + (size_t)k * 128 + nn];   // transpose read
    unsigned short h = f2bf(v);
    unsigned short lo = f2bf(v - bf2f(h));
    wth[idx] = (short)h;
    wtl[idx] = (short)lo;
}

// ------- GEMM v7 (MFMA split-bf16): Y = Ag@Wl + X@Wr + b (+relu) -------
// fp32 via 3 bf16 products per matmul: Ah@Wh + Ah@Wl + Al@Wh (Al@Wl ~2^-18
// dropped). 256 thr / 4 waves, 64x128 tile, wave = 32 rows x 64 cols =
// 2x4 C-frags. K-chunks of 32. LDS 61.4 KB -> 2 blocks/CU.
// MFMA layouts [measured m89/m91/m120]: A: m=lane&15, k=quad*8+j;
// B: n=lane&15, k=quad*8+j; C/D: col=lane&15, row=quad*4+reg.
__global__ __launch_bounds__(256, 2) void gemm_kernel(
    const float* __restrict__ Ag, const float* __restrict__ X,
    const short* __restrict__ Wlh, const short* __restrict__ Wll,
    const short* __restrict__ Wrh, const short* __restrict__ Wrl,
    const float* __restrict__ bias, float* __restrict__ Y, int n, int do_relu) {
    __shared__ short sAgh[64][40], sAgl[64][40], sXh[64][40], sXl[64][40];
    __shared__ short sWlh[128][40], sWll[128][40], sWrh[128][40], sWrl[128][40];
    const int tid = threadIdx.x;
    const int lane = tid & 63;
    const int wave = tid >> 6;
    const int ln15 = lane & 15;
    const int quad = lane >> 4;
    const int row0 = blockIdx.x * 64;
    const int wr0 = (wave & 1) * 32;     // wave's row offset in tile
    const int wc0 = (wave >> 1) * 64;    // wave's col offset

    f32x4 acc[2][4];
#pragma unroll
    for (int i = 0; i < 2; ++i)
#pragma unroll
        for (int j = 0; j < 4; ++j) acc[i][j] = (f32x4)(0.f);

    // A staging assignment: thread -> (mat, row, k-half)
    const int sm = tid >> 7;            // 0=Ag, 1=X
    const int srow = (tid >> 1) & 63;
    const int sh = tid & 1;             // 16-float half of the 32-k chunk
    int arow = row0 + srow;
    if (arow >= n) arow = n - 1;
    const float* asrc = (sm ? X : Ag) + (size_t)arow * NDIM + sh * 16;
    short* dsthi = (sm ? &sXh[0][0] : &sAgh[0][0]) + srow * 40 + sh * 16;
    short* dstlo = (sm ? &sXl[0][0] : &sAgl[0][0]) + srow * 40 + sh * 16;

    // W staging assignment: 2 slots per thread, slot -> (wmat, wrow)
    const int wi0 = tid;                // slot 0
    const int wi1 = tid + 256;          // slot 1
    const int wm0 = wi0 >> 7, wrow0s = wi0 & 127;
    const int wm1 = wi1 >> 7, wrow1s = wi1 & 127;
    const short* wsrc0 = (wm0 == 0 ? Wlh : wm0 == 1 ? Wll : wm0 == 2 ? Wrh : Wrl) + wrow0s * 128;
    const short* wsrc1 = (wm1 == 0 ? Wlh : wm1 == 1 ? Wll : wm1 == 2 ? Wrh : Wrl) + wrow1s * 128;
    short* wdst0 = (wm0 == 0 ? &sWlh[0][0] : wm0 == 1 ? &sWll[0][0] : wm0 == 2 ? &sWrh[0][0] : &sWrl[0][0]) + wrow0s * 40;
    short* wdst1 = (wm1 == 0 ? &sWlh[0][0] : wm1 == 1 ? &sWll[0][0] : wm1 == 2 ? &sWrh[0][0] : &sWrl[0][0]) + wrow1s * 40;

    for (int k0 = 0; k0 < NDIM; k0 += 32) {
        // global reads for this chunk
        float4 f0 = *(const float4*)(asrc + k0);
        float4 f1 = *(const float4*)(asrc + k0 + 4);
        float4 f2 = *(const float4*)(asrc + k0 + 8);
        float4 f3 = *(const float4*)(asrc + k0 + 12);
        int4 wv0[2], wv1[2];
#pragma unroll
        for (int j = 0; j < 2; ++j) {
            wv0[j] = *(const int4*)(wsrc0 + k0 + j * 8);
            wv1[j] = *(const int4*)(wsrc1 + k0 + j * 8);
        }
        int4 wv0b[2], wv1b[2];
#pragma unroll
        for (int j = 0; j < 2; ++j) {
            wv0b[j] = *(const int4*)(wsrc0 + k0 + 16 + j * 8);
            wv1b[j] = *(const int4*)(wsrc1 + k0 + 16 + j * 8);
        }
        __syncthreads();
        // A split + LDS write
        {
            float vals[16] = {f0.x, f0.y, f0.z, f0.w, f1.x, f1.y, f1.z, f1.w,
                              f2.x, f2.y, f2.z, f2.w, f3.x, f3.y, f3.z, f3.w};
#pragma unroll
            for (int j = 0; j < 4; ++j) {
                unsigned short h[4], l[4];
#pragma unroll
                for (int m = 0; m < 4; ++m) {
                    float v = vals[j * 4 + m];
                    h[m] = f2bf(v);
                    l[m] = f2bf(v - bf2f(h[m]));
                }
                int2 wh = make_int2((int)(h[0] | ((unsigned)h[1] << 16)),
                                    (int)(h[2] | ((unsigned)h[3] << 16)));
                int2 wl = make_int2((int)(l[0] | ((unsigned)l[1] << 16)),
                                    (int)(l[2] | ((unsigned)l[3] << 16)));
                *(int2*)(dsthi + j * 4) = wh;
                *(int2*)(dstlo + j * 4) = wl;
            }
        }
        // W LDS write (copy, already bf16)
#pragma unroll
        for (int j = 0; j < 2; ++j) {
            ((int2*)(wdst0 + j * 8))[0] = make_int2(wv0[j].x, wv0[j].y);
            ((int2*)(wdst0 + j * 8))[1] = make_int2(wv0[j].z, wv0[j].w);
            ((int2*)(wdst1 + j * 8))[0] = make_int2(wv1[j].x, wv1[j].y);
            ((int2*)(wdst1 + j * 8))[1] = make_int2(wv1[j].z, wv1[j].w);
            ((int2*)(wdst0 + 16 + j * 8))[0] = make_int2(wv0b[j].x, wv0b[j].y);
            ((int2*)(wdst0 + 16 + j * 8))[1] = make_int2(wv0b[j].z, wv0b[j].w);
            ((int2*)(wdst1 + 16 + j * 8))[0] = make_int2(wv1b[j].x, wv1b[j].y);
            ((int2*)(wdst1 + 16 + j * 8))[1] = make_int2(wv1b[j].z, wv1b[j].w);
        }
        __syncthreads();

        // A fragments for this wave's 2 row-tiles
        s16x8 fAgh[2], fAgl[2], fXh[2], fXl[2];
#pragma unroll
        for (int rt = 0; rt < 2; ++rt) {
            const int r = wr0 + rt * 16 + ln15;
            const short* p;
            p = &sAgh[r][quad * 8];
            ((int2*)&fAgh[rt])[0] = *(const int2*)p; ((int2*)&fAgh[rt])[1] = *(const int2*)(p + 4);
            p = &sAgl[r][quad * 8];
            ((int2*)&fAgl[rt])[0] = *(const int2*)p; ((int2*)&fAgl[rt])[1] = *(const int2*)(p + 4);
            p = &sXh[r][quad * 8];
            ((int2*)&fXh[rt])[0] = *(const int2*)p; ((int2*)&fXh[rt])[1] = *(const int2*)(p + 4);
            p = &sXl[r][quad * 8];
            ((int2*)&fXl[rt])[0] = *(const int2*)p; ((int2*)&fXl[rt])[1] = *(const int2*)(p + 4);
        }
#pragma unroll
        for (int ct = 0; ct < 4; ++ct) {
            const int c = wc0 + ct * 16 + ln15;
            s16x8 blh, bll, brh, brl;
            const short* p;
            p = &sWlh[c][quad * 8];
            ((int2*)&blh)[0] = *(const int2*)p; ((int2*)&blh)[1] = *(const int2*)(p + 4);
            p = &sWll[c][quad * 8];
            ((int2*)&bll)[0] = *(const int2*)p; ((int2*)&bll)[1] = *(const int2*)(p + 4);
            p = &sWrh[c][quad * 8];
            ((int2*)&brh)[0] = *(const int2*)p; ((int2*)&brh)[1] = *(const int2*)(p + 4);
            p = &sWrl[c][quad * 8];
            ((int2*)&brl)[0] = *(const int2*)p; ((int2*)&brl)[1] = *(const int2*)(p + 4);
#pragma unroll
            for (int rt = 0; rt < 2; ++rt) {
                acc[rt][ct] = __builtin_amdgcn_mfma_f32_16x16x32_bf16(fAgh[rt], blh, acc[rt][ct], 0, 0, 0);
                acc[rt][ct] = __builtin_amdgcn_mfma_f32_16x16x32_bf16(fAgh[rt], bll, acc[rt][ct], 0, 0, 0);
                acc[rt][ct] = __builtin_amdgcn_mfma_f32_16x16x32_bf16(fAgl[rt], blh, acc[rt][ct], 0, 0, 0);
                acc[rt][ct] = __builtin_amdgcn_mfma_f32_16x16x32_bf16(fXh[rt], brh, acc[rt][ct], 0, 0, 0);
                acc[rt][ct] = __builtin_amdgcn_mfma_f32_16x16x32_bf16(fXh[rt], brl, acc[rt][ct], 0, 0, 0);
                acc[rt][ct] = __builtin_amdgcn_mfma_f32_16x16x32_bf16(fXl[rt], brh, acc[rt][ct], 0, 0, 0);
            }
        }
    }

    // epilogue: C/D layout col=lane&15, row=quad*4+reg [m89]
#pragma unroll
    for (int rt = 0; rt < 2; ++rt) {
#pragma unroll
        for (int ct = 0; ct < 4; ++ct) {
            const int col = wc0 + ct * 16 + ln15;
            const float bv = bias[col];
#pragma unroll
            for (int r = 0; r < 4; ++r) {
                const int grow = row0 + wr0 + rt * 16 + quad * 4 + r;
                if (grow < n) {
                    float v = acc[rt][ct][r] + bv;
                    if (do_relu) v = fmaxf(v, 0.f);
                    Y[(size_t)grow * NDIM + col] = v;
                }
            }
        }
    }
}

// ---------------- host launcher ----------------
extern "C" void kernel_launch(void* const* d_in, const int* in_sizes, int n_in,
                              void* d_out, int out_size, void* d_ws, size_t ws_size,
                              hipStream_t stream) {
    const float* x0   = (const float*)d_in[0];
    const int*   eraw = (const int*)d_in[1];
    const float* Wl   = (const float*)d_in[2];
    const float* bl   = (const float*)d_in[3];
    const float* Wr   = (const float*)d_in[4];
    float* out = (float*)d_out;

    const int N = in_sizes[0] / NDIM;   // 50000
    const int E = in_sizes[1] / 2;      // 600000

    auto align_up = [](size_t v) { return (v + 255) & ~(size_t)255; };
    char* p = (char*)d_ws;
    int* idx = (int*)p;                 p += align_up((size_t)2 * E * 4);
    int* deg = (int*)p;                 p += align_up((size_t)(N + 1) * 4);
    int* flag = deg + N;
    int* row_start = (int*)p;           p += align_up((size_t)(N + 1) * 4);
    int* cursor = (int*)p;              p += align_up((size_t)N * 4);
    int* ssrc = (int*)p;                p += align_up((size_t)E * 4);
    float* invd = (float*)p;            p += align_up((size_t)N * 4);
    int* partials = (int*)p;            p += align_up((size_t)1024 * 4);
    short* wth = (short*)p;             p += align_up((size_t)163840 * 2);
    short* wtl = (short*)p;             p += align_up((size_t)163840 * 2);
    float* buf0 = (float*)p;            p += align_up((size_t)N * NDIM * 4);
    float* buf1 = (float*)p;            p += align_up((size_t)N * NDIM * 4);

    const int nb = (N + 1023) / 1024;

    hipMemsetAsync(deg, 0, (size_t)N * 4, stream);
    detect_kernel<<<1, 256, 0, stream>>>(eraw, flag, E);
    convert_kernel<<<(2 * E + 255) / 256, 256, 0, stream>>>(eraw, flag, idx, 2 * E);
    hist_kernel<<<(E + 255) / 256, 256, 0, stream>>>(idx, deg, E);
    deg_reduce_kernel<<<nb, 256, 0, stream>>>(deg, partials, N);
    scan_partials_kernel<<<1, 1024, 0, stream>>>(partials, nb, row_start, N);
    deg_downsweep_kernel<<<nb, 256, 0, stream>>>(deg, partials, row_start, cursor, invd, N);
    scatter_kernel<<<(E + 255) / 256, 256, 0, stream>>>(idx, cursor, ssrc, E);
    presplit_kernel<<<640, 256, 0, stream>>>(Wl, Wr, wth, wtl, 163840);

    // Full-width 64-row-band gemm: all reads precede epilogue stores ->
    // in-place (Y == Ag) is safe (v4-verified launcher pattern).
    const float* xin = x0;
    for (int l = 0; l < 5; ++l) {
        float* ab = (l & 1) ? buf1 : buf0;
        aggregate_kernel<<<(N * 32 + 255) / 256, 256, 0, stream>>>(
            xin, row_start, ssrc, invd, ab, N);
        float* yo = (l == 4) ? out : ab;
        const short* wlh = wth + (size_t)l * 16384;
        const short* wll = wtl + (size_t)l * 16384;
        const short* wrh = wth + (size_t)(5 + l) * 16384;
        const short* wrl = wtl + (size_t)(5 + l) * 16384;
        gemm_kernel<<<(N + 63) / 64, 256, 0, stream>>>(
            ab, xin, wlh, wll, wrh, wrl,
            bl + (size_t)l * NDIM, yo, N, l < 4 ? 1 : 0);
        xin = yo;
    }
}